// Round 7
// baseline (392.602 us; speedup 1.0000x reference)
//
#include <hip/hip_runtime.h>
#include <hip/hip_bf16.h>
#include <cmath>

// out[b,o] = max(softplus(log_scale[o]),1e-4) * sum_k x[b,k]*W[o,k] + bias[o]
// B=32, K=N=8192, W ternary int32 [N,K] -> memory-bound on W (256 MB/launch).
// Round 7: exact m97 structure (HW-proven ~60 GB/s/CU staging incl. barrier
// drains at 3 blocks/CU): global_load_lds width-16 staging, 2-barrier
// single-buffer K-loop, 4 blocks/CU de-phasing (512 thr, <=64 VGPR). XOR
// swizzle on the DMA *global* chunk index gives conflict-free ds_read_b128
// without LDS padding (DMA forbids padding).

#define K_SZ   8192
#define N_SZ   8192
#define B_SZ   32
#define KSPLIT 16
#define KSPAN  (K_SZ / KSPLIT)   // 512 k per block
#define STEPS  (KSPAN / 64)      // 8 steps x 64 k
#define BN     128               // n-rows per block tile (16 per wave)

typedef __attribute__((ext_vector_type(8))) short bf16x8;
typedef __attribute__((ext_vector_type(4))) float f32x4;

__device__ __forceinline__ unsigned pack_rn(float lo, float hi) {
  unsigned ul = __builtin_bit_cast(unsigned, lo) + 0x8000u;
  unsigned uh = __builtin_bit_cast(unsigned, hi) + 0x8000u;
  return (ul >> 16) | (uh & 0xFFFF0000u);
}
__device__ __forceinline__ unsigned pack_w(int w0, int w1) {
  unsigned u0 = __builtin_bit_cast(unsigned, (float)w0);
  unsigned u1 = __builtin_bit_cast(unsigned, (float)w1);
  return (u0 >> 16) | (u1 & 0xFFFF0000u);
}

// async global->LDS DMA, 16 B/lane; LDS dest = wave-uniform base + lane*16
__device__ __forceinline__ void dma16(const int* g, int* l) {
  __builtin_amdgcn_global_load_lds(
      (const __attribute__((address_space(1))) unsigned*)g,
      (__attribute__((address_space(3))) unsigned*)l, 16, 0, 0);
}

// X fp32[32,8192] -> Xr bf16 chunks in MFMA A-frag order.
// Chunk c = kb*2 + mt: 1 KB; lane l holds X[mt*16+(l&15)][kb*32+(l>>4)*8..+8].
__global__ void xprep(const float* __restrict__ X, uint4* __restrict__ Xr) {
  int t = blockIdx.x * blockDim.x + threadIdx.x;
  int lane = t & 63, chunk = t >> 6;
  int kb = chunk >> 1, mt = chunk & 1;
  int row = mt * 16 + (lane & 15);
  int k0 = kb * 32 + (lane >> 4) * 8;
  const float* p = X + (size_t)row * K_SZ + k0;
  float4 a = *(const float4*)p;
  float4 b = *(const float4*)(p + 4);
  uint4 o;
  o.x = pack_rn(a.x, a.y); o.y = pack_rn(a.z, a.w);
  o.z = pack_rn(b.x, b.y); o.w = pack_rn(b.z, b.w);
  Xr[t] = o;
}

__global__ __launch_bounds__(512, 8) void tmm(
    const int*   __restrict__ W,
    const uint4* __restrict__ Xr,
    float*       __restrict__ part) {   // [KSPLIT][32][8192] fp32
  // 128 rows x 64 ints = 32 KB, no padding (DMA constraint). Global chunk
  // XOR-swizzle: LDS slot s of row p holds global 16B-chunk s ^ (p & 15).
  __shared__ int wlds[BN * 64];

  const int tid  = threadIdx.x;
  const int w    = tid >> 6;       // wave 0..7
  const int lane = tid & 63;
  const int q    = lane >> 4;
  const int r    = lane & 15;
  const int nb   = blockIdx.x * BN;
  const int kh   = blockIdx.y;

  // DMA: wave w stages rows 16w..16w+15 via 4 instrs; instr j: lane l ->
  // row p = 16w+4j+(l>>4), global chunk ((l&15) ^ (p&15)), LDS slot (l&15).
  const int* gp[4];
  int*       lb[4];
  #pragma unroll
  for (int j = 0; j < 4; ++j) {
    int p  = 16 * w + 4 * j + (lane >> 4);
    int c  = (lane & 15) ^ (p & 15);
    gp[j] = W + (size_t)(nb + p) * K_SZ + (size_t)kh * KSPAN + c * 4;
    lb[j] = &wlds[(16 * w + 4 * j) * 64];
  }

  // prologue: DMA step 0
  #pragma unroll
  for (int j = 0; j < 4; ++j) dma16(gp[j], lb[j]);

  f32x4 acc0 = {0.f, 0.f, 0.f, 0.f};   // batches 0..15
  f32x4 acc1 = {0.f, 0.f, 0.f, 0.f};   // batches 16..31
  const int rowbase = (16 * w + r) * 64;   // wave consumes rows 16w+r (= col o)

  for (int h = 0; h < STEPS; ++h) {
    __syncthreads();   // DMA h landed (vmcnt drain; other blocks cover the CU)

    const int kg = kh * (KSPAN / 32) + h * 2;   // global 32-k block index
    // A-frags (Xr is 512 KB, L2-hot; consumed by MFMA below)
    uint4 a00 = Xr[(size_t)((kg + 0) * 2 + 0) * 64 + lane];
    uint4 a01 = Xr[(size_t)((kg + 0) * 2 + 1) * 64 + lane];
    uint4 a10 = Xr[(size_t)((kg + 1) * 2 + 0) * 64 + lane];
    uint4 a11 = Xr[(size_t)((kg + 1) * 2 + 1) * 64 + lane];

    #pragma unroll
    for (int kb2 = 0; kb2 < 2; ++kb2) {
      // B-frag: row 16w+r, ints kb2*32 + q*8 .. +7 = chunks (kb2*8+2q, +1)
      int s0 = (kb2 * 8 + 2 * q)     ^ r;
      int s1 = (kb2 * 8 + 2 * q + 1) ^ r;
      int4 lo = *(const int4*)&wlds[rowbase + s0 * 4];
      int4 hi = *(const int4*)&wlds[rowbase + s1 * 4];
      union { unsigned u[4]; bf16x8 v; } Bf;
      Bf.u[0] = pack_w(lo.x, lo.y); Bf.u[1] = pack_w(lo.z, lo.w);
      Bf.u[2] = pack_w(hi.x, hi.y); Bf.u[3] = pack_w(hi.z, hi.w);
      uint4 am0 = kb2 ? a10 : a00;
      uint4 am1 = kb2 ? a11 : a01;
      acc0 = __builtin_amdgcn_mfma_f32_16x16x32_bf16(
                 __builtin_bit_cast(bf16x8, am0), Bf.v, acc0, 0, 0, 0);
      acc1 = __builtin_amdgcn_mfma_f32_16x16x32_bf16(
                 __builtin_bit_cast(bf16x8, am1), Bf.v, acc1, 0, 0, 0);
    }

    __syncthreads();   // all waves done reading wlds
    if (h + 1 < STEPS) {
      #pragma unroll
      for (int j = 0; j < 4; ++j) dma16(gp[j] + (h + 1) * 64, lb[j]);
    }
  }

  // per-kh partials, coalesced stores (no atomics)
  const int o = nb + 16 * w + r;        // C/D: col = lane&15
  float* pb = part + (size_t)kh * B_SZ * N_SZ + o;
  #pragma unroll
  for (int rg = 0; rg < 4; ++rg) {      // C/D: row = (lane>>4)*4 + reg
    pb[(size_t)(q * 4 + rg) * N_SZ]      = acc0[rg];
    pb[(size_t)(16 + q * 4 + rg) * N_SZ] = acc1[rg];
  }
}

__global__ void reduce_k(const float* __restrict__ part,
                         const float* __restrict__ ls,
                         const float* __restrict__ bias,
                         float* __restrict__ out) {
  int idx = blockIdx.x * 256 + threadIdx.x;   // idx = b*8192 + o
  int o = idx & (N_SZ - 1);
  float s = 0.f;
  #pragma unroll
  for (int kh = 0; kh < KSPLIT; ++kh)
    s += part[(size_t)kh * B_SZ * N_SZ + idx];
  float sp = log1pf(expf(ls[o]));
  out[idx] = s * fmaxf(sp, 1e-4f) + bias[o];
}

extern "C" void kernel_launch(void* const* d_in, const int* in_sizes, int n_in,
                              void* d_out, int out_size, void* d_ws, size_t ws_size,
                              hipStream_t stream) {
  const float* X  = (const float*)d_in[0];
  const float* ls = (const float*)d_in[1];
  const float* bs = (const float*)d_in[2];
  const int*   W  = (const int*)d_in[3];
  float* out  = (float*)d_out;
  uint4* Xr   = (uint4*)d_ws;                         // 512 KB
  float* part = (float*)((char*)d_ws + (512 << 10));  // 16 MB

  xprep<<<128, 256, 0, stream>>>(X, Xr);
  dim3 grid(N_SZ / BN, KSPLIT);
  tmm<<<grid, 512, 0, stream>>>(W, Xr, part);
  reduce_k<<<(B_SZ * N_SZ) / 256, 256, 0, stream>>>(part, ls, bs, out);
}